// Round 9
// baseline (499.811 us; speedup 1.0000x reference)
//
#include <hip/hip_runtime.h>
#include <hip/hip_bf16.h>

#define B_  32
#define S_  4096
#define H_  1024
#define NH_ 16
#define DK_ 64
#define NCH 32                            // chunks of 128 rows
#define ROWS 128
#define TILE 4                            // rows per LDS tile
#define NT (ROWS / TILE)                  // 32 tiles per chunk
#define NBUF 3

// workspace layout (float offsets)
#define Q_OFF  0
#define T_OFF  (Q_OFF + B_*H_)            // q: B*H
#define C_OFF  (T_OFF + B_*NH_*H_)        // t: B*NH*H
#define YP_OFF (C_OFF + B_*NH_)           // c: B*NH
#define ML_OFF (YP_OFF + NCH*B_*NH_*H_)   // y_part: NCH*B*NH*H (64 MB)
#define Y2_OFF (ML_OFF + NCH*B_*2*NH_)    // ml stats
#define OP_OFF (Y2_OFF + B_*NH_*H_)       // reduced y: B*NH*H

#define DOT4(a, v) ((a).x*(v).x + (a).y*(v).y + (a).z*(v).z + (a).w*(v).w)

// async global->LDS 16B per lane; LDS base must be wave-uniform
__device__ __forceinline__ void load_lds16(const float* g, float* l) {
  __builtin_amdgcn_global_load_lds(
      (const __attribute__((address_space(1))) void*)g,
      (__attribute__((address_space(3))) void*)l, 16, 0, 0);
}

// ---------------- kernel 1: q[b,i] = x[b,S-1,:] . Wq[i,:] + bq[i] ----------
__global__ __launch_bounds__(256) void k_q(const float* __restrict__ x,
                                           const float* __restrict__ Wq,
                                           const float* __restrict__ bq,
                                           float* __restrict__ q) {
  __shared__ __align__(16) float xl[4 * H_];
  int islab = blockIdx.x, bg = blockIdx.y, tid = threadIdx.x;
  #pragma unroll
  for (int k = 0; k < 4; ++k) {
    int idx4 = k * 256 + tid;
    int bl = idx4 >> 8, col4 = idx4 & 255;
    *(float4*)&xl[bl * H_ + col4 * 4] =
        *(const float4*)(x + (((size_t)(bg * 4 + bl)) * S_ + (S_ - 1)) * H_ + col4 * 4);
  }
  __syncthreads();
  int d = tid >> 2, p = tid & 3;
  int i = islab * 64 + d;
  const float* w = Wq + (size_t)i * H_ + p * 256;
  float acc[4] = {0.f, 0.f, 0.f, 0.f};
  #pragma unroll 4
  for (int jj = 0; jj < 256; jj += 4) {
    float4 wv = *(const float4*)(w + jj);
    #pragma unroll
    for (int bl = 0; bl < 4; ++bl) {
      float4 xv = *(const float4*)&xl[bl * H_ + p * 256 + jj];
      acc[bl] += DOT4(xv, wv);
    }
  }
  #pragma unroll
  for (int bl = 0; bl < 4; ++bl) {
    acc[bl] += __shfl_xor(acc[bl], 1);
    acc[bl] += __shfl_xor(acc[bl], 2);
  }
  if (p == 0) {
    float bias = bq[i];
    #pragma unroll
    for (int bl = 0; bl < 4; ++bl)
      q[(size_t)(bg * 4 + bl) * H_ + i] = acc[bl] + bias;
  }
}

// -------- kernel 2: t[b,h,j] = sum_d q[b,h,d]*Wk[h*64+d, j]; c[b,h]=q.bk ---
__global__ __launch_bounds__(256) void k_t(const float* __restrict__ q,
                                           const float* __restrict__ Wk,
                                           const float* __restrict__ bk,
                                           float* __restrict__ t,
                                           float* __restrict__ c) {
  __shared__ __align__(16) float qh[B_ * DK_];   // 8 KB
  __shared__ __align__(16) float bkh[DK_];
  int js = blockIdx.x, h = blockIdx.y, tid = threadIdx.x;
  #pragma unroll
  for (int k = 0; k < 2; ++k) {
    int idx4 = k * 256 + tid;
    int bl = idx4 >> 4, d4 = idx4 & 15;
    *(float4*)&qh[bl * DK_ + d4 * 4] =
        *(const float4*)(q + (size_t)bl * H_ + h * DK_ + d4 * 4);
  }
  if (tid < 16)
    *(float4*)&bkh[tid * 4] = *(const float4*)(bk + h * DK_ + tid * 4);
  __syncthreads();

  if (js == 0 && tid < B_) {
    float cc = 0.f;
    for (int d = 0; d < DK_; ++d) cc += qh[tid * DK_ + d] * bkh[d];
    c[tid * NH_ + h] = cc;
  }

  int bh = tid >> 7;                    // batch half: 0 or 1
  int j = js * 128 + (tid & 127);
  float acc[16];
  #pragma unroll
  for (int bl = 0; bl < 16; ++bl) acc[bl] = 0.f;
  for (int d = 0; d < DK_; ++d) {
    float wv = Wk[((size_t)(h * DK_ + d)) * H_ + j];
    #pragma unroll
    for (int bl = 0; bl < 16; ++bl) acc[bl] += qh[(bh * 16 + bl) * DK_ + d] * wv;
  }
  #pragma unroll
  for (int bl = 0; bl < 16; ++bl)
    t[((size_t)((bh * 16 + bl) * NH_ + h)) * H_ + j] = acc[bl];
}

// ---- kernel 3 (fused flash pass, in-register softmax, counted-vmcnt
// 2-deep pipeline): 256 thr, lane = (head h = wv*4 + (ln>>4), cg = ln&15).
// Phase A: score dot over cols cg*64..+63 for 4 rows, shfl_xor reduce over
// the 16 cg lanes -> every lane holds full scores; m/l/es per-lane
// (cg-redundant, no LDS). Phase B: lane accumulates ya[16 x float4] =
// (head h, cols cg*64..+63) from the same LDS cols. One barrier per tile.
// LDS x-tile XOR-swizzled via pre-swizzled GLOBAL source (linear LDS dest):
// LDS slot cg*16+(k^cg) holds natural col4 cg*16+k.
__global__ __launch_bounds__(256) void k_flash(const float* __restrict__ x,
                                               const float* __restrict__ t,
                                               const float* __restrict__ c,
                                               float* __restrict__ ypart,
                                               float* __restrict__ mlpart) {
  __shared__ __align__(16) float xb[NBUF * TILE * H_];   // 48 KB

  int ch = blockIdx.x, b = blockIdx.y, tid = threadIdx.x;
  int wv = tid >> 6, ln = tid & 63;
  int hh = ln >> 4, cg = ln & 15;
  int h = wv * 4 + hh;

  const float* xg = x + ((size_t)b * S_ + (size_t)ch * ROWS) * H_;

  // staging swizzle: lane's LDS slot f = wv*64+ln -> global col4 beta*16+(sig^beta)
  int beta = wv * 4 + (ln >> 4);
  int sig = ln & 15;
  int goff = (beta * 16 + (sig ^ beta)) * 4;   // float offset within row

  // t fragment: head h, cols cg*64..+63, natural order
  float4 tf[16];
  const float* tg = t + ((size_t)b * NH_ + h) * H_ + cg * 64;
  #pragma unroll
  for (int k = 0; k < 16; ++k)
    tf[k] = *(const float4*)(tg + k * 4);

  float c_h = c[b * NH_ + h];

  float4 ya[16];
  #pragma unroll
  for (int k = 0; k < 16; ++k) { ya[k].x = ya[k].y = ya[k].z = ya[k].w = 0.f; }
  float m_r = -3.4e38f, l_r = 0.f;

#define STAGE(tl, bufi)                                                       \
  {                                                                           \
    const float* xrow_ = xg + (size_t)(tl) * TILE * H_;                       \
    _Pragma("unroll") for (int k_ = 0; k_ < TILE; ++k_)                       \
        load_lds16(xrow_ + (size_t)k_ * H_ + goff,                            \
                   &xb[(bufi) * (TILE * H_) + k_ * H_ + wv * 256]);           \
  }

  // prologue: stage tiles 0 and 1
  STAGE(0, 0);
  STAGE(1, 1);

  int bcur = 0;
  #pragma unroll 1
  for (int u = 0; u < NT; ++u) {
    // wait for tile u's loads (leave tile u+1 in flight), then sync all waves
    if (u == NT - 1)
      asm volatile("s_waitcnt vmcnt(0)" ::: "memory");
    else
      asm volatile("s_waitcnt vmcnt(4)" ::: "memory");
    __builtin_amdgcn_s_barrier();

    // prefetch tile u+2 into the buffer freed at iteration u-1
    int bnext2 = bcur + 2 >= NBUF ? bcur + 2 - NBUF : bcur + 2;
    if (u + 2 < NT) STAGE(u + 2, bnext2);

    const float* xt = &xb[bcur * (TILE * H_)];

    // ---- phase A: scores for 4 rows, head h, cols cg*64..+63 ----
    float scr[TILE];
    #pragma unroll
    for (int s = 0; s < TILE; ++s) scr[s] = 0.f;
    #pragma unroll
    for (int k = 0; k < 16; ++k) {
      int sl = (cg * 16 + (k ^ cg)) * 4;
      float4 tv = tf[k];
      #pragma unroll
      for (int s = 0; s < TILE; ++s) {
        float4 xv = *(const float4*)&xt[s * H_ + sl];
        scr[s] += DOT4(xv, tv);
      }
    }
    #pragma unroll
    for (int s = 0; s < TILE; ++s) {
      float a = scr[s];
      a += __shfl_xor(a, 1);
      a += __shfl_xor(a, 2);
      a += __shfl_xor(a, 4);
      a += __shfl_xor(a, 8);
      scr[s] = (a + c_h) * 0.125f;
    }

    // ---- in-register online softmax (cg-redundant) ----
    float tmax = fmaxf(fmaxf(scr[0], scr[1]), fmaxf(scr[2], scr[3]));
    float mnew = fmaxf(m_r, tmax);
    float fac = __expf(m_r - mnew);
    float es[TILE];
    float sume = 0.f;
    #pragma unroll
    for (int s = 0; s < TILE; ++s) { es[s] = __expf(scr[s] - mnew); sume += es[s]; }
    m_r = mnew;
    l_r = l_r * fac + sume;

    // ---- phase B: rescale + accumulate (same cols, own head) ----
    #pragma unroll
    for (int k = 0; k < 16; ++k) {
      ya[k].x *= fac; ya[k].y *= fac; ya[k].z *= fac; ya[k].w *= fac;
    }
    #pragma unroll
    for (int k = 0; k < 16; ++k) {
      int sl = (cg * 16 + (k ^ cg)) * 4;
      #pragma unroll
      for (int s = 0; s < TILE; ++s) {
        float4 xv = *(const float4*)&xt[s * H_ + sl];
        ya[k].x += es[s] * xv.x; ya[k].y += es[s] * xv.y;
        ya[k].z += es[s] * xv.z; ya[k].w += es[s] * xv.w;
      }
    }

    bcur = bcur + 1 >= NBUF ? 0 : bcur + 1;
  }

  // epilogue: lane owns (head h, cols cg*64..+63)
  float* yo = ypart + ((size_t)(ch * B_ + b)) * NH_ * H_ + (size_t)h * H_ + cg * 64;
  #pragma unroll
  for (int k = 0; k < 16; ++k)
    *(float4*)(yo + k * 4) = ya[k];
  if (cg == 0) {
    mlpart[((size_t)(ch * B_ + b)) * (2 * NH_) + h * 2 + 0] = m_r;
    mlpart[((size_t)(ch * B_ + b)) * (2 * NH_) + h * 2 + 1] = l_r;
  }
#undef STAGE
}

// ---- kernel 4: y2[b,h,:] = (sum_ch w_ch * y_part[ch]) / L  (512 blocks) ---
__global__ __launch_bounds__(256) void k_yred(const float* __restrict__ ypart,
                                              const float* __restrict__ mlpart,
                                              float* __restrict__ y2) {
  int h = blockIdx.x, b = blockIdx.y, tid = threadIdx.x;
  float mg = -3.4e38f;
  for (int ch = 0; ch < NCH; ++ch)
    mg = fmaxf(mg, mlpart[((size_t)(ch * B_ + b)) * (2 * NH_) + h * 2]);
  float L = 0.f;
  float4 acc; acc.x = acc.y = acc.z = acc.w = 0.f;
  for (int ch = 0; ch < NCH; ++ch) {
    float mc = mlpart[((size_t)(ch * B_ + b)) * (2 * NH_) + h * 2 + 0];
    float lc = mlpart[((size_t)(ch * B_ + b)) * (2 * NH_) + h * 2 + 1];
    float w = __expf(mc - mg);
    L += w * lc;
    float4 v = *(const float4*)(ypart +
        ((size_t)(ch * B_ + b)) * NH_ * H_ + (size_t)h * H_ + tid * 4);
    acc.x += w * v.x; acc.y += w * v.y; acc.z += w * v.z; acc.w += w * v.w;
  }
  float inv = 1.f / L;
  acc.x *= inv; acc.y *= inv; acc.z *= inv; acc.w *= inv;
  *(float4*)(y2 + ((size_t)(b * NH_ + h)) * H_ + tid * 4) = acc;
}

// -------- kernel 5: op[b,h*64+d] = Wv[h*64+d,:].y2[b,h,:] + bv -------------
__global__ __launch_bounds__(256) void k_vproj(const float* __restrict__ y2,
                                               const float* __restrict__ Wv,
                                               const float* __restrict__ bv,
                                               float* __restrict__ op) {
  __shared__ __align__(16) float yl[4 * H_];
  int h = blockIdx.x, bg = blockIdx.y, tid = threadIdx.x;
  #pragma unroll
  for (int k = 0; k < 4; ++k) {
    int idx4 = k * 256 + tid;
    int bl = idx4 >> 8, col4 = idx4 & 255;
    *(float4*)&yl[bl * H_ + col4 * 4] =
        *(const float4*)(y2 + ((size_t)((bg * 4 + bl) * NH_ + h)) * H_ + col4 * 4);
  }
  __syncthreads();
  int d = tid >> 2, p = tid & 3;
  const float* w = Wv + ((size_t)(h * DK_ + d)) * H_ + p * 256;
  float acc[4] = {0.f, 0.f, 0.f, 0.f};
  #pragma unroll 4
  for (int jj = 0; jj < 256; jj += 4) {
    float4 wv = *(const float4*)(w + jj);
    #pragma unroll
    for (int bl = 0; bl < 4; ++bl) {
      float4 yv = *(const float4*)&yl[bl * H_ + p * 256 + jj];
      acc[bl] += DOT4(yv, wv);
    }
  }
  #pragma unroll
  for (int bl = 0; bl < 4; ++bl) {
    acc[bl] += __shfl_xor(acc[bl], 1);
    acc[bl] += __shfl_xor(acc[bl], 2);
  }
  if (p == 0) {
    float bias = bv[h * DK_ + d];
    #pragma unroll
    for (int bl = 0; bl < 4; ++bl)
      op[(size_t)(bg * 4 + bl) * H_ + h * DK_ + d] = acc[bl] + bias;
  }
}

// -------- kernel 6: out[b,i] = Wo[i,:].out_pre[b,:] + bo[i] ----------------
__global__ __launch_bounds__(256) void k_out(const float* __restrict__ op,
                                             const float* __restrict__ Wo,
                                             const float* __restrict__ bo,
                                             float* __restrict__ out) {
  __shared__ __align__(16) float ul[4 * H_];
  int islab = blockIdx.x, bg = blockIdx.y, tid = threadIdx.x;
  #pragma unroll
  for (int k = 0; k < 4; ++k) {
    int idx4 = k * 256 + tid;
    int bl = idx4 >> 8, col4 = idx4 & 255;
    *(float4*)&ul[bl * H_ + col4 * 4] =
        *(const float4*)(op + (size_t)(bg * 4 + bl) * H_ + col4 * 4);
  }
  __syncthreads();
  int d = tid >> 2, p = tid & 3;
  int i = islab * 64 + d;
  const float* w = Wo + (size_t)i * H_ + p * 256;
  float acc[4] = {0.f, 0.f, 0.f, 0.f};
  #pragma unroll 4
  for (int jj = 0; jj < 256; jj += 4) {
    float4 wv = *(const float4*)(w + jj);
    #pragma unroll
    for (int bl = 0; bl < 4; ++bl) {
      float4 uv = *(const float4*)&ul[bl * H_ + p * 256 + jj];
      acc[bl] += DOT4(uv, wv);
    }
  }
  #pragma unroll
  for (int bl = 0; bl < 4; ++bl) {
    acc[bl] += __shfl_xor(acc[bl], 1);
    acc[bl] += __shfl_xor(acc[bl], 2);
  }
  if (p == 0) {
    float bias = bo[i];
    #pragma unroll
    for (int bl = 0; bl < 4; ++bl)
      out[(size_t)(bg * 4 + bl) * H_ + i] = acc[bl] + bias;
  }
}

extern "C" void kernel_launch(void* const* d_in, const int* in_sizes, int n_in,
                              void* d_out, int out_size, void* d_ws, size_t ws_size,
                              hipStream_t stream) {
  const float* x  = (const float*)d_in[0];
  const float* Wq = (const float*)d_in[1];
  const float* bq = (const float*)d_in[2];
  const float* Wk = (const float*)d_in[3];
  const float* bk = (const float*)d_in[4];
  const float* Wv = (const float*)d_in[5];
  const float* bv = (const float*)d_in[6];
  const float* Wo = (const float*)d_in[7];
  const float* bo = (const float*)d_in[8];
  float* out = (float*)d_out;
  float* ws = (float*)d_ws;

  float* q  = ws + Q_OFF;
  float* t  = ws + T_OFF;
  float* c  = ws + C_OFF;
  float* yp = ws + YP_OFF;
  float* ml = ws + ML_OFF;
  float* y2 = ws + Y2_OFF;
  float* op = ws + OP_OFF;

  k_q<<<dim3(16, B_ / 4), 256, 0, stream>>>(x, Wq, bq, q);
  k_t<<<dim3(8, NH_), 256, 0, stream>>>(q, Wk, bk, t, c);
  k_flash<<<dim3(NCH, B_), 256, 0, stream>>>(x, t, c, yp, ml);
  k_yred<<<dim3(NH_, B_), 256, 0, stream>>>(yp, ml, y2);
  k_vproj<<<dim3(NH_, B_ / 4), 256, 0, stream>>>(y2, Wv, bv, op);
  k_out<<<dim3(16, B_ / 4), 256, 0, stream>>>(op, Wo, bo, out);
}

// Round 10
// 287.161 us; speedup vs baseline: 1.7405x; 1.7405x over previous
//
#include <hip/hip_runtime.h>
#include <hip/hip_bf16.h>

#define B_  32
#define S_  4096
#define H_  1024
#define NH_ 16
#define DK_ 64
#define NCH 32                            // chunks of 128 rows
#define ROWS 128
#define TILE 4                            // rows per register tile
#define NT (ROWS / TILE)                  // 32 tiles per chunk

// workspace layout (float offsets)
#define Q_OFF  0
#define T_OFF  (Q_OFF + B_*H_)            // q: B*H
#define YP_OFF (T_OFF + B_*NH_*H_)        // t: B*NH*H
#define ML_OFF (YP_OFF + NCH*B_*NH_*H_)   // y_part: NCH*B*NH*H (64 MB)
#define Y2_OFF (ML_OFF + NCH*B_*2*NH_)    // ml stats
#define OP_OFF (Y2_OFF + B_*NH_*H_)       // reduced y: B*NH*H

#define DOT4(a, v) ((a).x*(v).x + (a).y*(v).y + (a).z*(v).z + (a).w*(v).w)

// butterfly-add via DPP (VALU pipe, no LDS). CTRL: 0xB1=xor1, 0x4E=xor2,
// 0x141=row_half_mirror (pairs quads), 0x140=row_mirror (pairs 8-groups).
template <int CTRL>
__device__ __forceinline__ float dppadd(float v) {
  int mv = __builtin_amdgcn_update_dpp(0, __float_as_int(v), CTRL, 0xF, 0xF, true);
  return v + __int_as_float(mv);
}

// ---------------- kernel 1: q[b,i] = x[b,S-1,:] . Wq[i,:] + bq[i] ----------
__global__ __launch_bounds__(256) void k_q(const float* __restrict__ x,
                                           const float* __restrict__ Wq,
                                           const float* __restrict__ bq,
                                           float* __restrict__ q) {
  __shared__ __align__(16) float xl[4 * H_];
  int islab = blockIdx.x, bg = blockIdx.y, tid = threadIdx.x;
  #pragma unroll
  for (int k = 0; k < 4; ++k) {
    int idx4 = k * 256 + tid;
    int bl = idx4 >> 8, col4 = idx4 & 255;
    *(float4*)&xl[bl * H_ + col4 * 4] =
        *(const float4*)(x + (((size_t)(bg * 4 + bl)) * S_ + (S_ - 1)) * H_ + col4 * 4);
  }
  __syncthreads();
  int d = tid >> 2, p = tid & 3;
  int i = islab * 64 + d;
  const float* w = Wq + (size_t)i * H_ + p * 256;
  float acc[4] = {0.f, 0.f, 0.f, 0.f};
  #pragma unroll 4
  for (int jj = 0; jj < 256; jj += 4) {
    float4 wv = *(const float4*)(w + jj);
    #pragma unroll
    for (int bl = 0; bl < 4; ++bl) {
      float4 xv = *(const float4*)&xl[bl * H_ + p * 256 + jj];
      acc[bl] += DOT4(xv, wv);
    }
  }
  #pragma unroll
  for (int bl = 0; bl < 4; ++bl) {
    acc[bl] += __shfl_xor(acc[bl], 1);
    acc[bl] += __shfl_xor(acc[bl], 2);
  }
  if (p == 0) {
    float bias = bq[i];
    #pragma unroll
    for (int bl = 0; bl < 4; ++bl)
      q[(size_t)(bg * 4 + bl) * H_ + i] = acc[bl] + bias;
  }
}

// -------- kernel 2: t[b,h,j] = sum_d q[b,h,d]*Wk[h*64+d, j] ---------------
// (the q.bk bias term is softmax-invariant -> dropped entirely)
__global__ __launch_bounds__(256) void k_t(const float* __restrict__ q,
                                           const float* __restrict__ Wk,
                                           float* __restrict__ t) {
  __shared__ __align__(16) float qh[B_ * DK_];   // 8 KB
  int js = blockIdx.x, h = blockIdx.y, tid = threadIdx.x;
  #pragma unroll
  for (int k = 0; k < 2; ++k) {
    int idx4 = k * 256 + tid;
    int bl = idx4 >> 4, d4 = idx4 & 15;
    *(float4*)&qh[bl * DK_ + d4 * 4] =
        *(const float4*)(q + (size_t)bl * H_ + h * DK_ + d4 * 4);
  }
  __syncthreads();

  int bh = tid >> 7;                    // batch half: 0 or 1
  int j = js * 128 + (tid & 127);
  float acc[16];
  #pragma unroll
  for (int bl = 0; bl < 16; ++bl) acc[bl] = 0.f;
  for (int d = 0; d < DK_; ++d) {
    float wv = Wk[((size_t)(h * DK_ + d)) * H_ + j];
    #pragma unroll
    for (int bl = 0; bl < 16; ++bl) acc[bl] += qh[(bh * 16 + bl) * DK_ + d] * wv;
  }
  #pragma unroll
  for (int bl = 0; bl < 16; ++bl)
    t[((size_t)((bh * 16 + bl) * NH_ + h)) * H_ + j] = acc[bl];
}

// ---- kernel 3 (fused flash pass, all-register, zero LDS/barriers):
// 256 thr = 4 waves x 4 heads each. Lane owns cols ln*16..+15 for both the
// score partial-dot and the PV accumulation; x is read ONCE per wave per
// tile, perfectly coalesced (64B/lane); 64-lane score reduce via DPP
// (xor 1,2,4,8 on VALU pipe) + shfl_xor(16,32).
__global__ __launch_bounds__(256) void k_flash(const float* __restrict__ x,
                                               const float* __restrict__ t,
                                               float* __restrict__ ypart,
                                               float* __restrict__ mlpart) {
  int ch = blockIdx.x, b = blockIdx.y, tid = threadIdx.x;
  int wv = tid >> 6, ln = tid & 63;

  const float* xg = x + ((size_t)b * S_ + (size_t)ch * ROWS) * H_ + ln * 16;

  // t fragments: wave's 4 heads, lane's 16 cols
  float4 tf[4][4];
  #pragma unroll
  for (int hh = 0; hh < 4; ++hh) {
    const float* tg = t + ((size_t)b * NH_ + wv * 4 + hh) * H_ + ln * 16;
    #pragma unroll
    for (int j = 0; j < 4; ++j) tf[hh][j] = *(const float4*)(tg + j * 4);
  }

  float4 ya[4][4];
  #pragma unroll
  for (int hh = 0; hh < 4; ++hh)
    #pragma unroll
    for (int j = 0; j < 4; ++j) {
      ya[hh][j].x = 0.f; ya[hh][j].y = 0.f; ya[hh][j].z = 0.f; ya[hh][j].w = 0.f;
    }
  float m_r[4] = {-3.4e38f, -3.4e38f, -3.4e38f, -3.4e38f};
  float l_r[4] = {0.f, 0.f, 0.f, 0.f};

  #pragma unroll 1
  for (int u = 0; u < NT; ++u) {
    // x fragment: 4 rows x 64B/lane, coalesced; feeds BOTH phases from regs
    float4 xr[TILE][4];
    #pragma unroll
    for (int s = 0; s < TILE; ++s) {
      const float* xrow = xg + (size_t)(u * TILE + s) * H_;
      #pragma unroll
      for (int j = 0; j < 4; ++j) xr[s][j] = *(const float4*)(xrow + j * 4);
    }

    // phase A: partial dots (lane's 16 cols) for 4 heads x 4 rows
    float scr[4][TILE];
    #pragma unroll
    for (int hh = 0; hh < 4; ++hh)
      #pragma unroll
      for (int s = 0; s < TILE; ++s) {
        float a = DOT4(xr[s][0], tf[hh][0]);
        a += DOT4(xr[s][1], tf[hh][1]);
        a += DOT4(xr[s][2], tf[hh][2]);
        a += DOT4(xr[s][3], tf[hh][3]);
        scr[hh][s] = a;
      }

    // 64-lane butterfly reduce: every lane ends with the full dot
    #pragma unroll
    for (int hh = 0; hh < 4; ++hh)
      #pragma unroll
      for (int s = 0; s < TILE; ++s) {
        float a = scr[hh][s];
        a = dppadd<0xB1>(a);    // xor1 (quad_perm 1,0,3,2)
        a = dppadd<0x4E>(a);    // xor2 (quad_perm 2,3,0,1)
        a = dppadd<0x141>(a);   // pairs quads (row_half_mirror)
        a = dppadd<0x140>(a);   // pairs 8-groups (row_mirror)
        a += __shfl_xor(a, 16);
        a += __shfl_xor(a, 32);
        scr[hh][s] = a * 0.125f;
      }

    // in-register online softmax + PV accumulation per head
    #pragma unroll
    for (int hh = 0; hh < 4; ++hh) {
      float tmax = fmaxf(fmaxf(scr[hh][0], scr[hh][1]), fmaxf(scr[hh][2], scr[hh][3]));
      float mnew = fmaxf(m_r[hh], tmax);
      float fac = __expf(m_r[hh] - mnew);
      float e0 = __expf(scr[hh][0] - mnew);
      float e1 = __expf(scr[hh][1] - mnew);
      float e2 = __expf(scr[hh][2] - mnew);
      float e3 = __expf(scr[hh][3] - mnew);
      m_r[hh] = mnew;
      l_r[hh] = l_r[hh] * fac + (e0 + e1 + e2 + e3);
      #pragma unroll
      for (int j = 0; j < 4; ++j) {
        float4 y0 = ya[hh][j];
        y0.x = y0.x * fac + e0 * xr[0][j].x + e1 * xr[1][j].x + e2 * xr[2][j].x + e3 * xr[3][j].x;
        y0.y = y0.y * fac + e0 * xr[0][j].y + e1 * xr[1][j].y + e2 * xr[2][j].y + e3 * xr[3][j].y;
        y0.z = y0.z * fac + e0 * xr[0][j].z + e1 * xr[1][j].z + e2 * xr[2][j].z + e3 * xr[3][j].z;
        y0.w = y0.w * fac + e0 * xr[0][j].w + e1 * xr[1][j].w + e2 * xr[2][j].w + e3 * xr[3][j].w;
        ya[hh][j] = y0;
      }
    }
  }

  // epilogue: lane owns (4 heads, cols ln*16..+15)
  float* yo = ypart + ((size_t)(ch * B_ + b)) * NH_ * H_ + ln * 16;
  #pragma unroll
  for (int hh = 0; hh < 4; ++hh)
    #pragma unroll
    for (int j = 0; j < 4; ++j)
      *(float4*)(yo + (size_t)(wv * 4 + hh) * H_ + j * 4) = ya[hh][j];
  if (ln == 0) {
    #pragma unroll
    for (int hh = 0; hh < 4; ++hh) {
      size_t base = ((size_t)(ch * B_ + b)) * (2 * NH_) + (size_t)(wv * 4 + hh) * 2;
      mlpart[base + 0] = m_r[hh];
      mlpart[base + 1] = l_r[hh];
    }
  }
}

// ---- kernel 4: y2[b,h,:] = (sum_ch w_ch * y_part[ch]) / L  (512 blocks) ---
__global__ __launch_bounds__(256) void k_yred(const float* __restrict__ ypart,
                                              const float* __restrict__ mlpart,
                                              float* __restrict__ y2) {
  int h = blockIdx.x, b = blockIdx.y, tid = threadIdx.x;
  float mg = -3.4e38f;
  for (int ch = 0; ch < NCH; ++ch)
    mg = fmaxf(mg, mlpart[((size_t)(ch * B_ + b)) * (2 * NH_) + h * 2]);
  float L = 0.f;
  float4 acc; acc.x = acc.y = acc.z = acc.w = 0.f;
  for (int ch = 0; ch < NCH; ++ch) {
    float mc = mlpart[((size_t)(ch * B_ + b)) * (2 * NH_) + h * 2 + 0];
    float lc = mlpart[((size_t)(ch * B_ + b)) * (2 * NH_) + h * 2 + 1];
    float w = __expf(mc - mg);
    L += w * lc;
    float4 v = *(const float4*)(ypart +
        ((size_t)(ch * B_ + b)) * NH_ * H_ + (size_t)h * H_ + tid * 4);
    acc.x += w * v.x; acc.y += w * v.y; acc.z += w * v.z; acc.w += w * v.w;
  }
  float inv = 1.f / L;
  acc.x *= inv; acc.y *= inv; acc.z *= inv; acc.w *= inv;
  *(float4*)(y2 + ((size_t)(b * NH_ + h)) * H_ + tid * 4) = acc;
}

// -------- kernel 5: op[b,h*64+d] = Wv[h*64+d,:].y2[b,h,:] + bv -------------
__global__ __launch_bounds__(256) void k_vproj(const float* __restrict__ y2,
                                               const float* __restrict__ Wv,
                                               const float* __restrict__ bv,
                                               float* __restrict__ op) {
  __shared__ __align__(16) float yl[4 * H_];
  int h = blockIdx.x, bg = blockIdx.y, tid = threadIdx.x;
  #pragma unroll
  for (int k = 0; k < 4; ++k) {
    int idx4 = k * 256 + tid;
    int bl = idx4 >> 8, col4 = idx4 & 255;
    *(float4*)&yl[bl * H_ + col4 * 4] =
        *(const float4*)(y2 + ((size_t)((bg * 4 + bl) * NH_ + h)) * H_ + col4 * 4);
  }
  __syncthreads();
  int d = tid >> 2, p = tid & 3;
  const float* w = Wv + ((size_t)(h * DK_ + d)) * H_ + p * 256;
  float acc[4] = {0.f, 0.f, 0.f, 0.f};
  #pragma unroll 4
  for (int jj = 0; jj < 256; jj += 4) {
    float4 wv = *(const float4*)(w + jj);
    #pragma unroll
    for (int bl = 0; bl < 4; ++bl) {
      float4 yv = *(const float4*)&yl[bl * H_ + p * 256 + jj];
      acc[bl] += DOT4(yv, wv);
    }
  }
  #pragma unroll
  for (int bl = 0; bl < 4; ++bl) {
    acc[bl] += __shfl_xor(acc[bl], 1);
    acc[bl] += __shfl_xor(acc[bl], 2);
  }
  if (p == 0) {
    float bias = bv[h * DK_ + d];
    #pragma unroll
    for (int bl = 0; bl < 4; ++bl)
      op[(size_t)(bg * 4 + bl) * H_ + h * DK_ + d] = acc[bl] + bias;
  }
}

// -------- kernel 6: out[b,i] = Wo[i,:].out_pre[b,:] + bo[i] ----------------
__global__ __launch_bounds__(256) void k_out(const float* __restrict__ op,
                                             const float* __restrict__ Wo,
                                             const float* __restrict__ bo,
                                             float* __restrict__ out) {
  __shared__ __align__(16) float ul[4 * H_];
  int islab = blockIdx.x, bg = blockIdx.y, tid = threadIdx.x;
  #pragma unroll
  for (int k = 0; k < 4; ++k) {
    int idx4 = k * 256 + tid;
    int bl = idx4 >> 8, col4 = idx4 & 255;
    *(float4*)&ul[bl * H_ + col4 * 4] =
        *(const float4*)(op + (size_t)(bg * 4 + bl) * H_ + col4 * 4);
  }
  __syncthreads();
  int d = tid >> 2, p = tid & 3;
  int i = islab * 64 + d;
  const float* w = Wo + (size_t)i * H_ + p * 256;
  float acc[4] = {0.f, 0.f, 0.f, 0.f};
  #pragma unroll 4
  for (int jj = 0; jj < 256; jj += 4) {
    float4 wv = *(const float4*)(w + jj);
    #pragma unroll
    for (int bl = 0; bl < 4; ++bl) {
      float4 uv = *(const float4*)&ul[bl * H_ + p * 256 + jj];
      acc[bl] += DOT4(uv, wv);
    }
  }
  #pragma unroll
  for (int bl = 0; bl < 4; ++bl) {
    acc[bl] += __shfl_xor(acc[bl], 1);
    acc[bl] += __shfl_xor(acc[bl], 2);
  }
  if (p == 0) {
    float bias = bo[i];
    #pragma unroll
    for (int bl = 0; bl < 4; ++bl)
      out[(size_t)(bg * 4 + bl) * H_ + i] = acc[bl] + bias;
  }
}

extern "C" void kernel_launch(void* const* d_in, const int* in_sizes, int n_in,
                              void* d_out, int out_size, void* d_ws, size_t ws_size,
                              hipStream_t stream) {
  const float* x  = (const float*)d_in[0];
  const float* Wq = (const float*)d_in[1];
  const float* bq = (const float*)d_in[2];
  const float* Wk = (const float*)d_in[3];
  const float* Wv = (const float*)d_in[5];
  const float* bv = (const float*)d_in[6];
  const float* Wo = (const float*)d_in[7];
  const float* bo = (const float*)d_in[8];
  float* out = (float*)d_out;
  float* ws = (float*)d_ws;

  float* q  = ws + Q_OFF;
  float* t  = ws + T_OFF;
  float* yp = ws + YP_OFF;
  float* ml = ws + ML_OFF;
  float* y2 = ws + Y2_OFF;
  float* op = ws + OP_OFF;

  k_q<<<dim3(16, B_ / 4), 256, 0, stream>>>(x, Wq, bq, q);
  k_t<<<dim3(8, NH_), 256, 0, stream>>>(q, Wk, t);
  k_flash<<<dim3(NCH, B_), 256, 0, stream>>>(x, t, yp, ml);
  k_yred<<<dim3(NH_, B_), 256, 0, stream>>>(yp, ml, y2);
  k_vproj<<<dim3(NH_, B_ / 4), 256, 0, stream>>>(y2, Wv, bv, op);
  k_out<<<dim3(16, B_ / 4), 256, 0, stream>>>(op, Wo, bo, out);
}